// Round 1
// baseline (247.750 us; speedup 1.0000x reference)
//
#include <hip/hip_runtime.h>
#include <stdint.h>

#define NROWS 8192   // B*S
#define HDIM  128
#define KSUB  8
#define NC    4096
#define DSUB  16
#define OUTD  6

// ---------------- Kernel 1: MLP (h2 = relu(relu(z W1 + b1) W2 + b2)) -> x ----------------
__global__ __launch_bounds__(256) void mlp_kernel(
    const float* __restrict__ z, const float* __restrict__ W1, const float* __restrict__ b1,
    const float* __restrict__ W2, const float* __restrict__ b2,
    float* __restrict__ x, unsigned long long* __restrict__ minpack)
{
    __shared__ float h1s[32 * HDIM];
    const int t = threadIdx.x;
    const int row0 = blockIdx.x * 32;

    // init minpack: 256 blocks * 256 threads == 65536 == NROWS*KSUB
    minpack[blockIdx.x * 256 + t] = 0xFFFFFFFFFFFFFFFFull;

    #pragma unroll
    for (int e = 0; e < 16; ++e) {
        const int idx = e * 256 + t;
        const int r = idx >> 7, j = idx & 127;
        const int n = row0 + r;
        float acc = b1[j];
        acc = fmaf(z[n * 3 + 0], W1[0 * HDIM + j], acc);
        acc = fmaf(z[n * 3 + 1], W1[1 * HDIM + j], acc);
        acc = fmaf(z[n * 3 + 2], W1[2 * HDIM + j], acc);
        h1s[idx] = fmaxf(acc, 0.f);
    }
    __syncthreads();

    for (int e = 0; e < 16; ++e) {
        const int idx = e * 256 + t;
        const int r = idx >> 7, j = idx & 127;
        float a0 = b2[j], a1 = 0.f, a2 = 0.f, a3 = 0.f;
        const float* h1r = &h1s[r * HDIM];
        #pragma unroll
        for (int i = 0; i < HDIM; i += 4) {
            const float4 h = *(const float4*)&h1r[i];
            a0 = fmaf(h.x, W2[(i + 0) * HDIM + j], a0);
            a1 = fmaf(h.y, W2[(i + 1) * HDIM + j], a1);
            a2 = fmaf(h.z, W2[(i + 2) * HDIM + j], a2);
            a3 = fmaf(h.w, W2[(i + 3) * HDIM + j], a3);
        }
        x[(row0 + r) * HDIM + j] = fmaxf((a0 + a1) + (a2 + a3), 0.f);
    }
}

// ---------------- Kernel 2: per-(row,k) argmin over centroids ----------------
#define CHUNK 256
#define CPB   1024

__global__ __launch_bounds__(256) void argmin_kernel(
    const float* __restrict__ x, const float* __restrict__ centroids,
    unsigned long long* __restrict__ minpack)
{
    __shared__ float cs[CHUNK * DSUB];
    __shared__ float cn[CHUNK];
    const int t = threadIdx.x;
    const int rb = blockIdx.x;   // 0..15
    const int k  = blockIdx.y;   // 0..7
    const int cz = blockIdx.z;   // 0..3
    const int row0 = rb * 512 + t;

    float xr[2][DSUB];
    #pragma unroll
    for (int rr = 0; rr < 2; ++rr) {
        const float* xp = &x[(size_t)(row0 + rr * 256) * HDIM + k * DSUB];
        #pragma unroll
        for (int q = 0; q < DSUB; q += 4) {
            const float4 v = *(const float4*)&xp[q];
            xr[rr][q + 0] = v.x; xr[rr][q + 1] = v.y;
            xr[rr][q + 2] = v.z; xr[rr][q + 3] = v.w;
        }
    }

    float mv0 = 1e30f, mv1 = 1e30f;
    int   mi0 = 0,     mi1 = 0;
    const int cbase0 = cz * CPB;

    for (int ch = 0; ch < CPB; ch += CHUNK) {
        const int cb = cbase0 + ch;
        __syncthreads();
        const float4* gp = (const float4*)&centroids[((size_t)k * NC + cb) * DSUB];
        float4* sp = (float4*)cs;
        #pragma unroll
        for (int q = 0; q < 4; ++q) sp[t + q * 256] = gp[t + q * 256];
        __syncthreads();
        {
            const float* cp = &cs[t * DSUB];
            float nn = 0.f;
            #pragma unroll
            for (int d = 0; d < DSUB; ++d) nn = fmaf(cp[d], cp[d], nn);
            cn[t] = nn;
        }
        __syncthreads();

        #pragma unroll 2
        for (int cc = 0; cc < CHUNK; ++cc) {
            const float4 c0 = *(const float4*)&cs[cc * DSUB + 0];
            const float4 c1 = *(const float4*)&cs[cc * DSUB + 4];
            const float4 c2 = *(const float4*)&cs[cc * DSUB + 8];
            const float4 c3 = *(const float4*)&cs[cc * DSUB + 12];
            const float nrm = cn[cc];
            {
                float d0 = xr[0][0] * c0.x, d1 = xr[0][1] * c0.y, d2 = xr[0][2] * c0.z, d3 = xr[0][3] * c0.w;
                d0 = fmaf(xr[0][4],  c1.x, d0); d1 = fmaf(xr[0][5],  c1.y, d1);
                d2 = fmaf(xr[0][6],  c1.z, d2); d3 = fmaf(xr[0][7],  c1.w, d3);
                d0 = fmaf(xr[0][8],  c2.x, d0); d1 = fmaf(xr[0][9],  c2.y, d1);
                d2 = fmaf(xr[0][10], c2.z, d2); d3 = fmaf(xr[0][11], c2.w, d3);
                d0 = fmaf(xr[0][12], c3.x, d0); d1 = fmaf(xr[0][13], c3.y, d1);
                d2 = fmaf(xr[0][14], c3.z, d2); d3 = fmaf(xr[0][15], c3.w, d3);
                const float s = nrm - 2.f * ((d0 + d1) + (d2 + d3));
                if (s < mv0) { mv0 = s; mi0 = cb + cc; }
            }
            {
                float d0 = xr[1][0] * c0.x, d1 = xr[1][1] * c0.y, d2 = xr[1][2] * c0.z, d3 = xr[1][3] * c0.w;
                d0 = fmaf(xr[1][4],  c1.x, d0); d1 = fmaf(xr[1][5],  c1.y, d1);
                d2 = fmaf(xr[1][6],  c1.z, d2); d3 = fmaf(xr[1][7],  c1.w, d3);
                d0 = fmaf(xr[1][8],  c2.x, d0); d1 = fmaf(xr[1][9],  c2.y, d1);
                d2 = fmaf(xr[1][10], c2.z, d2); d3 = fmaf(xr[1][11], c2.w, d3);
                d0 = fmaf(xr[1][12], c3.x, d0); d1 = fmaf(xr[1][13], c3.y, d1);
                d2 = fmaf(xr[1][14], c3.z, d2); d3 = fmaf(xr[1][15], c3.w, d3);
                const float s = nrm - 2.f * ((d0 + d1) + (d2 + d3));
                if (s < mv1) { mv1 = s; mi1 = cb + cc; }
            }
        }
    }

    {
        unsigned u = __float_as_uint(mv0);
        u = (u & 0x80000000u) ? ~u : (u | 0x80000000u);
        atomicMin(&minpack[(size_t)row0 * KSUB + k],
                  ((unsigned long long)u << 32) | (unsigned)mi0);
    }
    {
        unsigned u = __float_as_uint(mv1);
        u = (u & 0x80000000u) ? ~u : (u | 0x80000000u);
        atomicMin(&minpack[(size_t)(row0 + 256) * KSUB + k],
                  ((unsigned long long)u << 32) | (unsigned)mi1);
    }
}

// ---------------- Kernel 3: LUT gather + sum + bias -> llr ----------------
__global__ __launch_bounds__(256) void out_kernel(
    const float* __restrict__ centroids, const float* __restrict__ W3,
    const float* __restrict__ b3, const unsigned long long* __restrict__ minpack,
    float* __restrict__ out)
{
    const int gid = blockIdx.x * 256 + threadIdx.x;
    const int n = gid / OUTD;
    const int o = gid - n * OUTD;
    float acc = b3[o];
    #pragma unroll
    for (int k = 0; k < KSUB; ++k) {
        const int code = (int)(minpack[(size_t)n * KSUB + k] & 0xFFFFFFFFull);
        const float* cp = &centroids[((size_t)k * NC + code) * DSUB];
        const float* wp = &W3[(k * DSUB) * OUTD + o];
        #pragma unroll
        for (int d = 0; d < DSUB; ++d)
            acc = fmaf(cp[d], wp[d * OUTD], acc);
    }
    out[gid] = acc;
}

extern "C" void kernel_launch(void* const* d_in, const int* in_sizes, int n_in,
                              void* d_out, int out_size, void* d_ws, size_t ws_size,
                              hipStream_t stream)
{
    const float* z  = (const float*)d_in[0];
    const float* W1 = (const float*)d_in[1];
    const float* b1 = (const float*)d_in[2];
    const float* W2 = (const float*)d_in[3];
    const float* b2 = (const float*)d_in[4];
    const float* ce = (const float*)d_in[5];
    const float* W3 = (const float*)d_in[6];
    const float* b3 = (const float*)d_in[7];

    float* x = (float*)d_ws;                                       // 4 MiB
    unsigned long long* minpack =
        (unsigned long long*)((char*)d_ws + (size_t)NROWS * HDIM * sizeof(float)); // +512 KiB

    hipLaunchKernelGGL(mlp_kernel, dim3(NROWS / 32), dim3(256), 0, stream,
                       z, W1, b1, W2, b2, x, minpack);
    hipLaunchKernelGGL(argmin_kernel, dim3(16, 8, 4), dim3(256), 0, stream,
                       x, ce, minpack);
    hipLaunchKernelGGL(out_kernel, dim3((NROWS * OUTD) / 256), dim3(256), 0, stream,
                       ce, W3, b3, minpack, (float*)d_out);
}

// Round 2
// 200.589 us; speedup vs baseline: 1.2351x; 1.2351x over previous
//
#include <hip/hip_runtime.h>
#include <stdint.h>

#define NROWS 8192   // B*S
#define HDIM  128
#define KSUB  8
#define NC    4096
#define DSUB  16
#define OUTD  6

// ws layout:
//   x      : NROWS*HDIM fp32      (4 MiB)
//   minpack: NROWS*KSUB u64       (512 KiB)
//   cnorm  : KSUB*NC fp32         (128 KiB)

// ---------------- Kernel 1: MLP + centroid norms + minpack init ----------------
// grid 256 blocks x 256 thr; 32 rows/block. Phase B is a 4x4 register-tiled GEMM
// with W2 staged in LDS (the old version thrashed L1 with ~2048 VMEM loads/thread).
__global__ __launch_bounds__(256) void mlp_kernel(
    const float* __restrict__ z, const float* __restrict__ W1, const float* __restrict__ b1,
    const float* __restrict__ W2, const float* __restrict__ b2,
    const float* __restrict__ centroids,
    float* __restrict__ x, float* __restrict__ cnorm,
    unsigned long long* __restrict__ minpack)
{
    __shared__ float h1s[32 * HDIM];    // 16 KiB
    __shared__ float w2s[HDIM * HDIM];  // 64 KiB
    const int t = threadIdx.x;
    const int row0 = blockIdx.x * 32;

    // init minpack: 256 blocks * 256 threads == NROWS*KSUB
    minpack[blockIdx.x * 256 + t] = 0xFFFFFFFFFFFFFFFFull;

    // centroid norms (blocks 0..127 cover KSUB*NC = 32768 centroids)
    if (blockIdx.x < (KSUB * NC) / 256) {
        const int g = blockIdx.x * 256 + t;
        const float4* cp = (const float4*)&centroids[(size_t)g * DSUB];
        float nn = 0.f;
        #pragma unroll
        for (int q = 0; q < 4; ++q) {
            const float4 v = cp[q];
            nn = fmaf(v.x, v.x, nn); nn = fmaf(v.y, v.y, nn);
            nn = fmaf(v.z, v.z, nn); nn = fmaf(v.w, v.w, nn);
        }
        cnorm[g] = nn;
    }

    // stage W2 (16384 floats, 16 float4/thread, coalesced)
    {
        const float4* g4 = (const float4*)W2;
        float4* s4 = (float4*)w2s;
        #pragma unroll
        for (int q = 0; q < 16; ++q) s4[t + q * 256] = g4[t + q * 256];
    }

    // phase A: h1 = relu(z @ W1 + b1) into LDS (32x128)
    #pragma unroll
    for (int e = 0; e < 16; ++e) {
        const int idx = e * 256 + t;
        const int r = idx >> 7, j = idx & 127;
        const int n = row0 + r;
        float acc = b1[j];
        acc = fmaf(z[n * 3 + 0], W1[0 * HDIM + j], acc);
        acc = fmaf(z[n * 3 + 1], W1[1 * HDIM + j], acc);
        acc = fmaf(z[n * 3 + 2], W1[2 * HDIM + j], acc);
        h1s[idx] = fmaxf(acc, 0.f);
    }
    __syncthreads();

    // phase B: 4 rows x 4 cols per thread; 8 ds_read_b128 per 64 FMA
    const int c4 = (t & 31) * 4;   // col base (32 groups x 4 = 128)
    const int r4 = (t >> 5) * 4;   // row base (8 groups x 4 = 32)
    float acc[4][4];
    #pragma unroll
    for (int a = 0; a < 4; ++a)
        #pragma unroll
        for (int b = 0; b < 4; ++b) acc[a][b] = 0.f;

    for (int k4 = 0; k4 < HDIM; k4 += 4) {
        float hh[4][4], ww[4][4];
        #pragma unroll
        for (int q = 0; q < 4; ++q) {
            const float4 v = *(const float4*)&h1s[(r4 + q) * HDIM + k4];
            hh[q][0] = v.x; hh[q][1] = v.y; hh[q][2] = v.z; hh[q][3] = v.w;
        }
        #pragma unroll
        for (int p = 0; p < 4; ++p) {
            const float4 v = *(const float4*)&w2s[(k4 + p) * HDIM + c4];
            ww[p][0] = v.x; ww[p][1] = v.y; ww[p][2] = v.z; ww[p][3] = v.w;
        }
        #pragma unroll
        for (int q = 0; q < 4; ++q)
            #pragma unroll
            for (int p = 0; p < 4; ++p) {
                acc[q][0] = fmaf(hh[q][p], ww[p][0], acc[q][0]);
                acc[q][1] = fmaf(hh[q][p], ww[p][1], acc[q][1]);
                acc[q][2] = fmaf(hh[q][p], ww[p][2], acc[q][2]);
                acc[q][3] = fmaf(hh[q][p], ww[p][3], acc[q][3]);
            }
    }

    const float4 bb = *(const float4*)&b2[c4];
    #pragma unroll
    for (int q = 0; q < 4; ++q) {
        float4 o;
        o.x = fmaxf(acc[q][0] + bb.x, 0.f);
        o.y = fmaxf(acc[q][1] + bb.y, 0.f);
        o.z = fmaxf(acc[q][2] + bb.z, 0.f);
        o.w = fmaxf(acc[q][3] + bb.w, 0.f);
        *(float4*)&x[(size_t)(row0 + r4 + q) * HDIM + c4] = o;
    }
}

// ---------------- Kernel 2: per-(row,k) argmin over centroids ----------------
// grid (8 rowblocks, 8 k, 16 c-splits) = 1024 blocks -> 4 blocks/CU, 16 waves/CU.
// 4 rows/thread (ILP + amortized LDS broadcast reads). Norms precomputed.
#define RPT 4

__global__ __launch_bounds__(256) void argmin_kernel(
    const float* __restrict__ x, const float* __restrict__ centroids,
    const float* __restrict__ cnorm, unsigned long long* __restrict__ minpack)
{
    __shared__ float cs[256 * DSUB];  // 16 KiB
    __shared__ float cn[256];         // 1 KiB
    const int t = threadIdx.x;
    const int rb = blockIdx.x;   // 0..7
    const int k  = blockIdx.y;   // 0..7
    const int cz = blockIdx.z;   // 0..15
    const int row0 = rb * 1024 + t;
    const int cb = cz * 256;

    // load 4 x-fragments into registers
    float xr[RPT][DSUB];
    #pragma unroll
    for (int rr = 0; rr < RPT; ++rr) {
        const float* xp = &x[(size_t)(row0 + rr * 256) * HDIM + k * DSUB];
        #pragma unroll
        for (int q = 0; q < DSUB; q += 4) {
            const float4 v = *(const float4*)&xp[q];
            xr[rr][q + 0] = v.x; xr[rr][q + 1] = v.y;
            xr[rr][q + 2] = v.z; xr[rr][q + 3] = v.w;
        }
    }

    // stage 256 centroids + norms (coalesced)
    {
        const float4* gp = (const float4*)&centroids[((size_t)k * NC + cb) * DSUB];
        float4* sp = (float4*)cs;
        #pragma unroll
        for (int q = 0; q < 4; ++q) sp[t + q * 256] = gp[t + q * 256];
        cn[t] = cnorm[k * NC + cb + t];
    }
    __syncthreads();

    float mv[RPT]; int mi[RPT];
    #pragma unroll
    for (int rr = 0; rr < RPT; ++rr) { mv[rr] = 1e30f; mi[rr] = 0; }

    for (int cc = 0; cc < 256; ++cc) {
        const float4 c0 = *(const float4*)&cs[cc * DSUB + 0];
        const float4 c1 = *(const float4*)&cs[cc * DSUB + 4];
        const float4 c2 = *(const float4*)&cs[cc * DSUB + 8];
        const float4 c3 = *(const float4*)&cs[cc * DSUB + 12];
        const float nrm = cn[cc];
        #pragma unroll
        for (int rr = 0; rr < RPT; ++rr) {
            float d;
            d = xr[rr][0] * c0.x;
            d = fmaf(xr[rr][1],  c0.y, d);
            d = fmaf(xr[rr][2],  c0.z, d);
            d = fmaf(xr[rr][3],  c0.w, d);
            d = fmaf(xr[rr][4],  c1.x, d);
            d = fmaf(xr[rr][5],  c1.y, d);
            d = fmaf(xr[rr][6],  c1.z, d);
            d = fmaf(xr[rr][7],  c1.w, d);
            d = fmaf(xr[rr][8],  c2.x, d);
            d = fmaf(xr[rr][9],  c2.y, d);
            d = fmaf(xr[rr][10], c2.z, d);
            d = fmaf(xr[rr][11], c2.w, d);
            d = fmaf(xr[rr][12], c3.x, d);
            d = fmaf(xr[rr][13], c3.y, d);
            d = fmaf(xr[rr][14], c3.z, d);
            d = fmaf(xr[rr][15], c3.w, d);
            const float s = fmaf(d, -2.f, nrm);
            if (s < mv[rr]) { mv[rr] = s; mi[rr] = cb + cc; }  // strict < => lowest idx wins
        }
    }

    #pragma unroll
    for (int rr = 0; rr < RPT; ++rr) {
        unsigned u = __float_as_uint(mv[rr]);
        u = (u & 0x80000000u) ? ~u : (u | 0x80000000u);  // order-preserving float->uint
        atomicMin(&minpack[(size_t)(row0 + rr * 256) * KSUB + k],
                  ((unsigned long long)u << 32) | (unsigned)mi[rr]);
    }
}

// ---------------- Kernel 3: LUT gather + sum + bias -> llr ----------------
__global__ __launch_bounds__(256) void out_kernel(
    const float* __restrict__ centroids, const float* __restrict__ W3,
    const float* __restrict__ b3, const unsigned long long* __restrict__ minpack,
    float* __restrict__ out)
{
    const int gid = blockIdx.x * 256 + threadIdx.x;
    const int n = gid / OUTD;
    const int o = gid - n * OUTD;
    float acc = b3[o];
    #pragma unroll
    for (int k = 0; k < KSUB; ++k) {
        const int code = (int)(minpack[(size_t)n * KSUB + k] & 0xFFFFFFFFull);
        const float* cp = &centroids[((size_t)k * NC + code) * DSUB];
        const float* wp = &W3[(k * DSUB) * OUTD + o];
        #pragma unroll
        for (int d = 0; d < DSUB; ++d)
            acc = fmaf(cp[d], wp[d * OUTD], acc);
    }
    out[gid] = acc;
}

extern "C" void kernel_launch(void* const* d_in, const int* in_sizes, int n_in,
                              void* d_out, int out_size, void* d_ws, size_t ws_size,
                              hipStream_t stream)
{
    const float* z  = (const float*)d_in[0];
    const float* W1 = (const float*)d_in[1];
    const float* b1 = (const float*)d_in[2];
    const float* W2 = (const float*)d_in[3];
    const float* b2 = (const float*)d_in[4];
    const float* ce = (const float*)d_in[5];
    const float* W3 = (const float*)d_in[6];
    const float* b3 = (const float*)d_in[7];

    char* ws = (char*)d_ws;
    float* x = (float*)ws;                                                    // 4 MiB
    unsigned long long* minpack = (unsigned long long*)(ws + (size_t)NROWS * HDIM * 4);  // +512 KiB
    float* cnorm = (float*)(ws + (size_t)NROWS * HDIM * 4 + (size_t)NROWS * KSUB * 8);   // +128 KiB

    hipLaunchKernelGGL(mlp_kernel, dim3(NROWS / 32), dim3(256), 0, stream,
                       z, W1, b1, W2, b2, ce, x, cnorm, minpack);
    hipLaunchKernelGGL(argmin_kernel, dim3(8, 8, 16), dim3(256), 0, stream,
                       x, ce, cnorm, minpack);
    hipLaunchKernelGGL(out_kernel, dim3((NROWS * OUTD) / 256), dim3(256), 0, stream,
                       ce, W3, b3, minpack, (float*)d_out);
}